// Round 1
// baseline (321.500 us; speedup 1.0000x reference)
//
#include <hip/hip_runtime.h>
#include <stdint.h>

// AxialBottleneck: B=4, C=128, H=W=128, heads=8, dh=16.
// K1: xp = x + pos_h + pos_w -> xh[B,W,H,C] bf16, xw[B,H,W,C] bf16; weights -> Wt[out][in] bf16.
// K2: fused per-sequence MHA (grid 1024 = 512 H-seqs + 512 W-seqs), in-place update of xh/xw.
// K3: out = oh + ow + x  (transpose back to [B,C,H,W]).

typedef __attribute__((ext_vector_type(8))) short short8;   // 8 bf16 = 4 VGPRs (MFMA A/B frag)
typedef __attribute__((ext_vector_type(4))) short short4_;
typedef __attribute__((ext_vector_type(4))) float f32x4;

#define DEVFN static __device__ __forceinline__

DEVFN uint16_t f2bf(float f) {  // RNE f32->bf16
  uint32_t u = __builtin_bit_cast(uint32_t, f);
  u = (u + 0x7FFFu + ((u >> 16) & 1u)) >> 16;
  return (uint16_t)u;
}
DEVFN float bf2f(uint16_t h) {
  uint32_t u = ((uint32_t)h) << 16;
  return __builtin_bit_cast(float, u);
}
// XOR-swizzled byte address inside a 128x128 bf16 (256B-row) LDS tile (G4 fix for
// the 32-way conflict of row-major D=128 tiles). boff in [0,256).
DEVFN uint32_t sw(int row, int boff) {
  return (uint32_t)((row << 8) | (boff ^ ((row & 7) << 4)));
}

// ---------------------------------------------------------------- K1: prep
__global__ __launch_bounds__(512) void k_prep(
    const float* __restrict__ x, const float* __restrict__ ph, const float* __restrict__ pw,
    const float* __restrict__ w0, const float* __restrict__ w1, const float* __restrict__ w2,
    const float* __restrict__ w3, const float* __restrict__ w4, const float* __restrict__ w5,
    const float* __restrict__ w6, const float* __restrict__ w7,
    uint16_t* __restrict__ xh, uint16_t* __restrict__ xw, uint16_t* __restrict__ wt)
{
  __shared__ float T[128 * 133];   // odd dword stride 133 -> conflict-light transpose
  int bid = blockIdx.x, t = threadIdx.x;
  if (bid < 512) {
    int b = bid >> 7, h = bid & 127;
    const float* xb = x + ((size_t)b * 128) * 16384 + h * 128;
    #pragma unroll
    for (int p = 0; p < 8; ++p) {
      int c = (t >> 5) + (p << 4);
      int w0i = (t & 31) << 2;
      f32x4 xv = *(const f32x4*)(xb + (size_t)c * 16384 + w0i);
      float phv = ph[c * 128 + h];
      f32x4 pwv = *(const f32x4*)(pw + c * 128 + w0i);
      #pragma unroll
      for (int j = 0; j < 4; ++j) T[c * 133 + w0i + j] = xv[j] + phv + pwv[j];
    }
    __syncthreads();
    #pragma unroll
    for (int p = 0; p < 16; ++p) {
      int c2 = (t & 63) << 1;             // lanes vary c -> odd-stride column reads conflict-free
      int w = (t >> 6) + (p << 3);
      float a0 = T[c2 * 133 + w], a1 = T[(c2 + 1) * 133 + w];
      uint32_t pk = (uint32_t)f2bf(a0) | ((uint32_t)f2bf(a1) << 16);
      size_t ih = ((((size_t)b * 128 + w) * 128 + h) * 128 + c2) >> 1;
      size_t iw = ((((size_t)b * 128 + h) * 128 + w) * 128 + c2) >> 1;
      ((uint32_t*)xh)[ih] = pk;
      ((uint32_t*)xw)[iw] = pk;
    }
  } else {
    int m = bid - 512;                    // 8 weight matrices -> Wt[out][in] bf16
    const float* Ws;
    switch (m) {
      case 0: Ws = w0; break; case 1: Ws = w1; break; case 2: Ws = w2; break;
      case 3: Ws = w3; break; case 4: Ws = w4; break; case 5: Ws = w5; break;
      case 6: Ws = w6; break; default: Ws = w7; break;
    }
    uint16_t* dst = wt + m * 16384;
    #pragma unroll
    for (int p = 0; p < 8; ++p) {
      int in = (t >> 5) + (p << 4);
      int o0 = (t & 31) << 2;
      f32x4 wv = *(const f32x4*)(Ws + in * 128 + o0);
      #pragma unroll
      for (int j = 0; j < 4; ++j) dst[(o0 + j) * 128 + in] = f2bf(wv[j]);
    }
  }
}

// ---------------------------------------------------------------- K2: fused per-sequence MHA
__global__ __launch_bounds__(512) void k_attn(
    const uint16_t* __restrict__ wt, uint16_t* __restrict__ xh, uint16_t* __restrict__ xw,
    const float* __restrict__ bo_h, const float* __restrict__ bo_w)
{
  __shared__ uint16_t sm[81920];          // 160 KiB exactly: Xb,Qb,Kb,Vt,Ab
  uint16_t* Xb = sm;                      // X, later O (row-major [token][c])
  uint16_t* Qb = sm + 16384;              // Q row-major; reused for Y in epilogue
  uint16_t* Kb = sm + 32768;              // K row-major
  uint16_t* Vt = sm + 49152;              // V transposed [c][token]
  uint16_t* Ab = sm + 65536;              // softmax(P) row-major (per-wave bands)

  int bid = blockIdx.x;
  int dir = bid >> 9, sid = bid & 511;
  uint16_t* xbuf = (dir ? xw : xh) + (size_t)sid * 16384;
  const uint16_t* Wq = wt + dir * 65536;
  const uint16_t* Wk = Wq + 16384;
  const uint16_t* Wv = Wq + 32768;
  const uint16_t* Wo = Wq + 49152;
  const float* bo = dir ? bo_w : bo_h;

  int t = threadIdx.x, l = t & 63, wid = t >> 6, band = wid << 4;
  int lr = l & 15, lg = l >> 4;
  const f32x4 zf = {0.f, 0.f, 0.f, 0.f};

  // stage X (32 KB) -> swizzled LDS
  #pragma unroll
  for (int i = 0; i < 4; ++i) {
    int fb = ((i << 9) | t) << 4;
    int row = fb >> 8, off = fb & 255;
    short8 v = *(const short8*)((const char*)xbuf + fb);
    *(short8*)((char*)Xb + sw(row, off)) = v;
  }
  __syncthreads();

  // A-frags of X for this wave's 16-row band (shared by Q/K/V GEMMs)
  short8 ax[4];
  {
    int ar = band | lr;
    #pragma unroll
    for (int kt = 0; kt < 4; ++kt)
      ax[kt] = *(const short8*)((const char*)Xb + sw(ar, (kt << 6) | (lg << 4)));
  }

  // GEMM1: Q = X@Wq, K = X@Wk, V = X@Wv  (B-frags straight from L2-hot global Wt)
  #pragma unroll 1
  for (int pj = 0; pj < 3; ++pj) {
    const uint16_t* Wp = (pj == 0) ? Wq : (pj == 1) ? Wk : Wv;
    #pragma unroll 1
    for (int tc = 0; tc < 8; ++tc) {
      f32x4 acc = zf;
      int wr = (tc << 4) | lr;
      #pragma unroll
      for (int kt = 0; kt < 4; ++kt) {
        short8 bf = *(const short8*)((const char*)Wp + (wr << 8) + (kt << 6) + (lg << 4));
        acc = __builtin_amdgcn_mfma_f32_16x16x32_bf16(ax[kt], bf, acc, 0, 0, 0);
      }
      if (pj < 2) {                       // Q,K row-major  (D layout: col=l&15, row=lg*4+j)
        uint16_t* dst = pj ? Kb : Qb;
        #pragma unroll
        for (int j = 0; j < 4; ++j) {
          int row = band + (lg << 2) + j;
          *(uint16_t*)((char*)dst + sw(row, wr << 1)) = f2bf(acc[j]);
        }
      } else {                            // V transposed: 4 consecutive tokens -> packed b64
        int r0 = band + (lg << 2);
        short4_ pk;
        pk[0] = (short)f2bf(acc[0]); pk[1] = (short)f2bf(acc[1]);
        pk[2] = (short)f2bf(acc[2]); pk[3] = (short)f2bf(acc[3]);
        *(short4_*)((char*)Vt + sw(wr, r0 << 1)) = pk;
      }
    }
  }
  __syncthreads();   // K,V visible to all waves; everything after is wave-private bands

  // head loop: S = (Q_h K_h^T)*0.25, softmax rows, O_h = P V_h
  #pragma unroll 1
  for (int h = 0; h < 8; ++h) {
    int hb = h << 5;                                  // byte offset of head's 16 channels
    short8 aq = {0,0,0,0,0,0,0,0};
    if (l < 32) aq = *(const short8*)((const char*)Qb + sw(band | lr, hb | (lg << 4)));
    f32x4 s[8];
    #pragma unroll
    for (int tc = 0; tc < 8; ++tc) {
      short8 bk = {0,0,0,0,0,0,0,0};                  // dh=16 < K=32: zero the upper half
      if (l < 32) bk = *(const short8*)((const char*)Kb + sw((tc << 4) | lr, hb | (lg << 4)));
      s[tc] = __builtin_amdgcn_mfma_f32_16x16x32_bf16(aq, bk, zf, 0, 0, 0);
    }
    #pragma unroll
    for (int j = 0; j < 4; ++j) {                     // row softmax: 8 in-lane + 4 shfl (cols=lane&15)
      float mj = -1e30f;
      #pragma unroll
      for (int tc = 0; tc < 8; ++tc) { s[tc][j] *= 0.25f; mj = fmaxf(mj, s[tc][j]); }
      mj = fmaxf(mj, __shfl_xor(mj, 1));
      mj = fmaxf(mj, __shfl_xor(mj, 2));
      mj = fmaxf(mj, __shfl_xor(mj, 4));
      mj = fmaxf(mj, __shfl_xor(mj, 8));
      float sum = 0.f;
      #pragma unroll
      for (int tc = 0; tc < 8; ++tc) { float e = __expf(s[tc][j] - mj); s[tc][j] = e; sum += e; }
      sum += __shfl_xor(sum, 1);
      sum += __shfl_xor(sum, 2);
      sum += __shfl_xor(sum, 4);
      sum += __shfl_xor(sum, 8);
      float r = __builtin_amdgcn_rcpf(sum);
      int row = band + (lg << 2) + j;
      #pragma unroll
      for (int tc = 0; tc < 8; ++tc)
        *(uint16_t*)((char*)Ab + sw(row, ((tc << 4) | lr) << 1)) = f2bf(s[tc][j] * r);
    }
    asm volatile("s_waitcnt lgkmcnt(0)" ::: "memory");
    f32x4 acco = zf;
    #pragma unroll
    for (int kt = 0; kt < 4; ++kt) {                  // O_h band += P band @ V_h
      short8 pa = *(const short8*)((const char*)Ab + sw(band | lr, (kt << 6) | (lg << 4)));
      short8 bv = *(const short8*)((const char*)Vt + sw((h << 4) | lr, (kt << 6) | (lg << 4)));
      acco = __builtin_amdgcn_mfma_f32_16x16x32_bf16(pa, bv, acco, 0, 0, 0);
    }
    int col = (h << 4) | lr;                          // write O column-block into Xb (X is dead)
    #pragma unroll
    for (int j = 0; j < 4; ++j) {
      int row = band + (lg << 2) + j;
      *(uint16_t*)((char*)Xb + sw(row, col << 1)) = f2bf(acco[j]);
    }
  }
  asm volatile("s_waitcnt lgkmcnt(0)" ::: "memory");

  // Y = O@Wo + bo  -> Qb (reuse), then coalesced write-back in place
  short8 ao[4];
  {
    int ar = band | lr;
    #pragma unroll
    for (int kt = 0; kt < 4; ++kt)
      ao[kt] = *(const short8*)((const char*)Xb + sw(ar, (kt << 6) | (lg << 4)));
  }
  #pragma unroll 1
  for (int tc = 0; tc < 8; ++tc) {
    f32x4 acc = zf;
    int wr = (tc << 4) | lr;
    #pragma unroll
    for (int kt = 0; kt < 4; ++kt) {
      short8 bf = *(const short8*)((const char*)Wo + (wr << 8) + (kt << 6) + (lg << 4));
      acc = __builtin_amdgcn_mfma_f32_16x16x32_bf16(ao[kt], bf, acc, 0, 0, 0);
    }
    float bov = bo[wr];
    #pragma unroll
    for (int j = 0; j < 4; ++j) {
      int row = band + (lg << 2) + j;
      *(uint16_t*)((char*)Qb + sw(row, wr << 1)) = f2bf(acc[j] + bov);
    }
  }
  asm volatile("s_waitcnt lgkmcnt(0)" ::: "memory");
  #pragma unroll
  for (int p = 0; p < 4; ++p) {                       // 1 KB coalesced stores per wave-pass
    int fb = (p << 10) | (l << 4);
    int row = band + (fb >> 8), off = fb & 255;
    short8 v = *(const short8*)((const char*)Qb + sw(row, off));
    *(short8*)((char*)xbuf + (row << 8) + off) = v;
  }
}

// ---------------------------------------------------------------- K3: combine
__global__ __launch_bounds__(512) void k_comb(
    const uint16_t* __restrict__ xh, const uint16_t* __restrict__ xw,
    const float* __restrict__ x, float* __restrict__ out)
{
  __shared__ float T[128 * 133];
  int bid = blockIdx.x, t = threadIdx.x;
  int b = bid >> 7, h = bid & 127;
  #pragma unroll 1
  for (int p = 0; p < 16; ++p) {
    int c2 = (t & 63) << 1;
    int w = (t >> 6) + (p << 3);
    uint32_t o2 = *(const uint32_t*)(xh + ((((size_t)b * 128 + w) * 128 + h) * 128 + c2));
    uint32_t y2 = *(const uint32_t*)(xw + ((((size_t)b * 128 + h) * 128 + w) * 128 + c2));
    T[c2 * 133 + w]       = bf2f((uint16_t)o2) + bf2f((uint16_t)y2);
    T[(c2 + 1) * 133 + w] = bf2f((uint16_t)(o2 >> 16)) + bf2f((uint16_t)(y2 >> 16));
  }
  __syncthreads();
  #pragma unroll 1
  for (int p = 0; p < 8; ++p) {
    int c = (t >> 5) + (p << 4);
    int w0i = (t & 31) << 2;
    size_t xi = ((size_t)b * 128 + c) * 16384 + (size_t)h * 128 + w0i;
    f32x4 xv = *(const f32x4*)(x + xi);
    f32x4 o;
    #pragma unroll
    for (int j = 0; j < 4; ++j) o[j] = T[c * 133 + w0i + j] + xv[j];
    *(f32x4*)(out + xi) = o;
  }
}

// ---------------------------------------------------------------- launch
extern "C" void kernel_launch(void* const* d_in, const int* in_sizes, int n_in,
                              void* d_out, int out_size, void* d_ws, size_t ws_size,
                              hipStream_t stream) {
  const float* x    = (const float*)d_in[0];
  const float* ph   = (const float*)d_in[1];
  const float* pw   = (const float*)d_in[2];
  const float* Wq_h = (const float*)d_in[3];
  const float* Wk_h = (const float*)d_in[4];
  const float* Wv_h = (const float*)d_in[5];
  const float* Wo_h = (const float*)d_in[6];
  const float* bo_h = (const float*)d_in[7];
  const float* Wq_w = (const float*)d_in[8];
  const float* Wk_w = (const float*)d_in[9];
  const float* Wv_w = (const float*)d_in[10];
  const float* Wo_w = (const float*)d_in[11];
  const float* bo_w = (const float*)d_in[12];
  float* out = (float*)d_out;

  uint16_t* xh = (uint16_t*)d_ws;          // 16 MB  [B,W,H,C] bf16, becomes oh in-place
  uint16_t* xw = xh + 8388608;             // 16 MB  [B,H,W,C] bf16, becomes ow in-place
  uint16_t* wt = xw + 8388608;             // 256 KB 8x Wt[out][in] bf16

  k_prep<<<520, 512, 0, stream>>>(x, ph, pw, Wq_h, Wk_h, Wv_h, Wo_h,
                                  Wq_w, Wk_w, Wv_w, Wo_w, xh, xw, wt);
  k_attn<<<1024, 512, 0, stream>>>(wt, xh, xw, bo_h, bo_w);
  k_comb<<<512, 512, 0, stream>>>(xh, xw, x, out);
}

// Round 9
// 305.075 us; speedup vs baseline: 1.0538x; 1.0538x over previous
//
#include <hip/hip_runtime.h>
#include <stdint.h>

// AxialBottleneck: B=4, C=128, H=W=128, heads=8, dh=16.
// K1: xp = x + pos_h + pos_w -> xh[B,W,H,C] bf16, xw[B,H,W,C] bf16; weights -> Wt[out][in] bf16.
// K2: fused per-sequence MHA, layout-closed K=16 MFMA chain, in-place update of xh/xw.
// K3: out = oh + ow + x  (transpose back to [B,C,H,W]).

typedef __attribute__((ext_vector_type(8))) short short8;   // 8 bf16 (MFMA K=32 frag)
typedef __attribute__((ext_vector_type(4))) short bf16x4;   // 4 bf16 (MFMA K=16 frag)
typedef __attribute__((ext_vector_type(4))) float f32x4;

#define DEVFN static __device__ __forceinline__

DEVFN uint16_t f2bf(float f) {  // RNE f32->bf16
  uint32_t u = __builtin_bit_cast(uint32_t, f);
  u = (u + 0x7FFFu + ((u >> 16) & 1u)) >> 16;
  return (uint16_t)u;
}
DEVFN float bf2f(uint16_t h) {
  uint32_t u = ((uint32_t)h) << 16;
  return __builtin_bit_cast(float, u);
}
DEVFN bf16x4 pack4(float a0, float a1, float a2, float a3) {
  bf16x4 r;
  r[0] = (short)f2bf(a0);
  r[1] = (short)f2bf(a1);
  r[2] = (short)f2bf(a2);
  r[3] = (short)f2bf(a3);
  return r;
}

// 16x16x16 bf16 MFMA: D[m][n] = sum_k A[m][k]B[n][k]; lane: A/B row = l&15,
// k = (l>>4)*4+e; D: col(n)=l&15, row(m)=(l>>4)*4+j  (same C/D map as K=32, m89).
DEVFN f32x4 mfma16(bf16x4 a, bf16x4 b, f32x4 c) {
#if __has_builtin(__builtin_amdgcn_mfma_f32_16x16x16bf16_1k)
  return __builtin_amdgcn_mfma_f32_16x16x16bf16_1k(a, b, c, 0, 0, 0);
#elif __has_builtin(__builtin_amdgcn_mfma_f32_16x16x16_bf16)
  return __builtin_amdgcn_mfma_f32_16x16x16_bf16(a, b, c, 0, 0, 0);
#else
  f32x4 d;
  asm volatile("s_nop 1\n\tv_mfma_f32_16x16x16_bf16 %0, %1, %2, %3\n\ts_nop 7\n\ts_nop 7"
               : "=v"(d) : "v"(a), "v"(b), "v"(c));
  return d;
#endif
}

// ---------------------------------------------------------------- K1: prep (unchanged)
__global__ __launch_bounds__(512) void k_prep(
    const float* __restrict__ x, const float* __restrict__ ph, const float* __restrict__ pw,
    const float* __restrict__ w0, const float* __restrict__ w1, const float* __restrict__ w2,
    const float* __restrict__ w3, const float* __restrict__ w4, const float* __restrict__ w5,
    const float* __restrict__ w6, const float* __restrict__ w7,
    uint16_t* __restrict__ xh, uint16_t* __restrict__ xw, uint16_t* __restrict__ wt)
{
  __shared__ float T[128 * 133];
  int bid = blockIdx.x, t = threadIdx.x;
  if (bid < 512) {
    int b = bid >> 7, h = bid & 127;
    const float* xb = x + ((size_t)b * 128) * 16384 + h * 128;
    #pragma unroll
    for (int p = 0; p < 8; ++p) {
      int c = (t >> 5) + (p << 4);
      int w0i = (t & 31) << 2;
      f32x4 xv = *(const f32x4*)(xb + (size_t)c * 16384 + w0i);
      float phv = ph[c * 128 + h];
      f32x4 pwv = *(const f32x4*)(pw + c * 128 + w0i);
      #pragma unroll
      for (int j = 0; j < 4; ++j) T[c * 133 + w0i + j] = xv[j] + phv + pwv[j];
    }
    __syncthreads();
    #pragma unroll
    for (int p = 0; p < 16; ++p) {
      int c2 = (t & 63) << 1;
      int w = (t >> 6) + (p << 3);
      float a0 = T[c2 * 133 + w], a1 = T[(c2 + 1) * 133 + w];
      uint32_t pk = (uint32_t)f2bf(a0) | ((uint32_t)f2bf(a1) << 16);
      size_t ih = ((((size_t)b * 128 + w) * 128 + h) * 128 + c2) >> 1;
      size_t iw = ((((size_t)b * 128 + h) * 128 + w) * 128 + c2) >> 1;
      ((uint32_t*)xh)[ih] = pk;
      ((uint32_t*)xw)[iw] = pk;
    }
  } else {
    int m = bid - 512;
    const float* Ws;
    switch (m) {
      case 0: Ws = w0; break; case 1: Ws = w1; break; case 2: Ws = w2; break;
      case 3: Ws = w3; break; case 4: Ws = w4; break; case 5: Ws = w5; break;
      case 6: Ws = w6; break; default: Ws = w7; break;
    }
    uint16_t* dst = wt + m * 16384;
    #pragma unroll
    for (int p = 0; p < 8; ++p) {
      int in = (t >> 5) + (p << 4);
      int o0 = (t & 31) << 2;
      f32x4 wv = *(const f32x4*)(Ws + in * 128 + o0);
      #pragma unroll
      for (int j = 0; j < 4; ++j) dst[(o0 + j) * 128 + in] = f2bf(wv[j]);
    }
  }
}

// ---------------------------------------------------------------- K2: fused MHA v2
// 64 KiB LDS (K + V^T), 2 blocks/CU. Layout-closed K=16 MFMA chain after GEMM1.
__global__ __launch_bounds__(512, 4) void k_attn(
    const uint16_t* __restrict__ wt, uint16_t* __restrict__ xh, uint16_t* __restrict__ xw,
    const float* __restrict__ bo_h, const float* __restrict__ bo_w)
{
  __shared__ uint16_t sm[32768];          // 64 KiB
  uint16_t* Kb = sm;                      // [token][ch]  swizzled, 32 KB
  uint16_t* Vt = sm + 16384;              // [ch][token]  swizzled, 32 KB

  int bid = blockIdx.x;
  int dir = bid >> 9, sid = bid & 511;
  uint16_t* xbuf = (dir ? xw : xh) + (size_t)sid * 16384;
  const char* Wq = (const char*)(wt + dir * 65536);
  const char* Wk = Wq + 32768;
  const char* Wv = Wq + 65536;
  const char* Wo = Wq + 98304;
  const float* bo = dir ? bo_w : bo_h;

  int t = threadIdx.x, l = t & 63, band = (t >> 6) << 4;
  int lr = l & 15, lg = l >> 4;
  int swz = (lr & 7) << 4;                // XOR swizzle keyed on row&7 == lr&7 everywhere
  const f32x4 zf = {0.f, 0.f, 0.f, 0.f};

  // ---- GEMM1: X row-frags straight from global (rows band+lr, 16B per kt)
  short8 ax[4];
  {
    const char* xr = (const char*)xbuf + ((band + lr) << 8) + (lg << 4);
    ax[0] = *(const short8*)(xr);
    ax[1] = *(const short8*)(xr + 64);
    ax[2] = *(const short8*)(xr + 128);
    ax[3] = *(const short8*)(xr + 192);
  }

  bf16x4 qf[8];                           // Q[band+lr][16tc+4lg+j] * 0.25*log2e
  const float cs = 0.36067376022f;        // 0.25 * log2(e)

  // Q (swapped: A=Wq rows=out-ch, B=X rows=q) -> registers, pre-scaled
  #pragma unroll 2
  for (int tc = 0; tc < 8; ++tc) {
    f32x4 a = zf;
    const char* wb = Wq + (((tc << 4) | lr) << 8) + (lg << 4);
    #pragma unroll
    for (int kt = 0; kt < 4; ++kt)
      a = __builtin_amdgcn_mfma_f32_16x16x32_bf16(*(const short8*)(wb + (kt << 6)), ax[kt], a, 0, 0, 0);
    qf[tc] = pack4(a[0] * cs, a[1] * cs, a[2] * cs, a[3] * cs);
  }
  // K (swapped) -> Kb[token band+lr][ch 16tc+4lg+j]
  #pragma unroll 2
  for (int tc = 0; tc < 8; ++tc) {
    f32x4 a = zf;
    const char* wb = Wk + (((tc << 4) | lr) << 8) + (lg << 4);
    #pragma unroll
    for (int kt = 0; kt < 4; ++kt)
      a = __builtin_amdgcn_mfma_f32_16x16x32_bf16(*(const short8*)(wb + (kt << 6)), ax[kt], a, 0, 0, 0);
    *(bf16x4*)((char*)Kb + ((band + lr) << 8) + (((tc << 5) | (lg << 3)) ^ swz)) =
        pack4(a[0], a[1], a[2], a[3]);
  }
  // V (normal: A=X, B=Wv) -> Vt[ch 16tc+lr][token band+4lg+j]
  #pragma unroll 2
  for (int tc = 0; tc < 8; ++tc) {
    f32x4 a = zf;
    const char* wb = Wv + (((tc << 4) | lr) << 8) + (lg << 4);
    #pragma unroll
    for (int kt = 0; kt < 4; ++kt)
      a = __builtin_amdgcn_mfma_f32_16x16x32_bf16(ax[kt], *(const short8*)(wb + (kt << 6)), a, 0, 0, 0);
    *(bf16x4*)((char*)Vt + (((tc << 4) | lr) << 8) + (((band << 1) | (lg << 3)) ^ swz)) =
        pack4(a[0], a[1], a[2], a[3]);
  }
  __syncthreads();   // only barrier: K,V visible; rest is register/LDS-read only

  f32x4 y[8];        // Y[band+lr][16tc+4lg+j], accumulated per head
  #pragma unroll
  for (int tc = 0; tc < 8; ++tc) y[tc] = zf;

  #pragma unroll 1
  for (int h = 0; h < 8; ++h) {
    // QK^T swapped: s[tt][j] = S*[q=band+lr][token 16tt+4lg+j] (pre-scaled, log2-domain)
    f32x4 s[8];
    #pragma unroll
    for (int tt = 0; tt < 8; ++tt) {
      bf16x4 kf = *(const bf16x4*)((const char*)Kb + (((tt << 4) | lr) << 8) +
                                   (((h << 5) | (lg << 3)) ^ swz));
      s[tt] = mfma16(kf, qf[h], zf);
    }
    // in-lane softmax over 32 tokens + 2 shfl_xor for the 4-lane (lg) group
    float mx = -3.0e38f;
    #pragma unroll
    for (int tt = 0; tt < 8; ++tt)
      #pragma unroll
      for (int j = 0; j < 4; ++j) mx = fmaxf(mx, s[tt][j]);
    mx = fmaxf(mx, __shfl_xor(mx, 16));
    mx = fmaxf(mx, __shfl_xor(mx, 32));
    float sum = 0.f;
    #pragma unroll
    for (int tt = 0; tt < 8; ++tt)
      #pragma unroll
      for (int j = 0; j < 4; ++j) {
        float p = __builtin_amdgcn_exp2f(s[tt][j] - mx);
        s[tt][j] = p; sum += p;
      }
    sum += __shfl_xor(sum, 16);
    sum += __shfl_xor(sum, 32);

    // PV: packed P-hat is directly the B-frag; A = Vt frags. o = O-hat[band+lr][16h+4lg+j]
    f32x4 o = zf;
    #pragma unroll
    for (int tt = 0; tt < 8; ++tt) {
      bf16x4 pt = pack4(s[tt][0], s[tt][1], s[tt][2], s[tt][3]);
      bf16x4 vf = *(const bf16x4*)((const char*)Vt + (((h << 4) | lr) << 8) +
                                   (((tt << 5) | (lg << 3)) ^ swz));
      o = mfma16(vf, pt, o);
    }
    float r = __builtin_amdgcn_rcpf(sum);
    bf16x4 ob = pack4(o[0] * r, o[1] * r, o[2] * r, o[3] * r);

    // per-head epilogue: Y += O_h @ Wo[h-slice]  (A = Wo rows=out-ch, B = ob)
    #pragma unroll
    for (int tc = 0; tc < 8; ++tc) {
      bf16x4 wf = *(const bf16x4*)(Wo + (((tc << 4) | lr) << 8) + (h << 5) + (lg << 3));
      y[tc] = mfma16(wf, ob, y[tc]);
    }
  }

  // bias + write back in place (8B per lane per tc, 32B-chunk coalesced)
  #pragma unroll
  for (int tc = 0; tc < 8; ++tc) {
    f32x4 bv = *(const f32x4*)(bo + (tc << 4) + (lg << 2));
    *(bf16x4*)((char*)xbuf + ((band + lr) << 8) + (tc << 5) + (lg << 3)) =
        pack4(y[tc][0] + bv[0], y[tc][1] + bv[1], y[tc][2] + bv[2], y[tc][3] + bv[3]);
  }
}

// ---------------------------------------------------------------- K3: combine (unchanged)
__global__ __launch_bounds__(512) void k_comb(
    const uint16_t* __restrict__ xh, const uint16_t* __restrict__ xw,
    const float* __restrict__ x, float* __restrict__ out)
{
  __shared__ float T[128 * 133];
  int bid = blockIdx.x, t = threadIdx.x;
  int b = bid >> 7, h = bid & 127;
  #pragma unroll 1
  for (int p = 0; p < 16; ++p) {
    int c2 = (t & 63) << 1;
    int w = (t >> 6) + (p << 3);
    uint32_t o2 = *(const uint32_t*)(xh + ((((size_t)b * 128 + w) * 128 + h) * 128 + c2));
    uint32_t y2 = *(const uint32_t*)(xw + ((((size_t)b * 128 + h) * 128 + w) * 128 + c2));
    T[c2 * 133 + w]       = bf2f((uint16_t)o2) + bf2f((uint16_t)y2);
    T[(c2 + 1) * 133 + w] = bf2f((uint16_t)(o2 >> 16)) + bf2f((uint16_t)(y2 >> 16));
  }
  __syncthreads();
  #pragma unroll 1
  for (int p = 0; p < 8; ++p) {
    int c = (t >> 5) + (p << 4);
    int w0i = (t & 31) << 2;
    size_t xi = ((size_t)b * 128 + c) * 16384 + (size_t)h * 128 + w0i;
    f32x4 xv = *(const f32x4*)(x + xi);
    f32x4 o;
    #pragma unroll
    for (int j = 0; j < 4; ++j) o[j] = T[c * 133 + w0i + j] + xv[j];
    *(f32x4*)(out + xi) = o;
  }
}

// ---------------------------------------------------------------- launch
extern "C" void kernel_launch(void* const* d_in, const int* in_sizes, int n_in,
                              void* d_out, int out_size, void* d_ws, size_t ws_size,
                              hipStream_t stream) {
  const float* x    = (const float*)d_in[0];
  const float* ph   = (const float*)d_in[1];
  const float* pw   = (const float*)d_in[2];
  const float* Wq_h = (const float*)d_in[3];
  const float* Wk_h = (const float*)d_in[4];
  const float* Wv_h = (const float*)d_in[5];
  const float* Wo_h = (const float*)d_in[6];
  const float* bo_h = (const float*)d_in[7];
  const float* Wq_w = (const float*)d_in[8];
  const float* Wk_w = (const float*)d_in[9];
  const float* Wv_w = (const float*)d_in[10];
  const float* Wo_w = (const float*)d_in[11];
  const float* bo_w = (const float*)d_in[12];
  float* out = (float*)d_out;

  uint16_t* xh = (uint16_t*)d_ws;          // 16 MB  [B,W,H,C] bf16, becomes oh in-place
  uint16_t* xw = xh + 8388608;             // 16 MB  [B,H,W,C] bf16, becomes ow in-place
  uint16_t* wt = xw + 8388608;             // 256 KB 8x Wt[out][in] bf16

  k_prep<<<520, 512, 0, stream>>>(x, ph, pw, Wq_h, Wk_h, Wv_h, Wo_h,
                                  Wq_w, Wk_w, Wv_w, Wo_w, xh, xw, wt);
  k_attn<<<1024, 512, 0, stream>>>(wt, xh, xw, bo_h, bo_w);
  k_comb<<<512, 512, 0, stream>>>(xh, xw, x, out);
}